// Round 1
// baseline (97.578 us; speedup 1.0000x reference)
//
#include <hip/hip_runtime.h>
#include <math.h>

#define BDIM 256
constexpr float GAMMA = 0.2f;
constexpr int Bn = 1024;
constexpr int Cn = 100000;
constexpr int Tn = 20;

// Kernel 1: one block per row. Online logsumexp over C, then small gather work.
__global__ __launch_bounds__(BDIM) void rll_row_kernel(
    const float* __restrict__ x, const int* __restrict__ y,
    float* __restrict__ ws) {
  const int b = blockIdx.x;
  const float* __restrict__ xr = x + (size_t)b * Cn;
  const float4* __restrict__ x4 = reinterpret_cast<const float4*>(xr);

  // --- online (m, s) logsumexp accumulation, float4 vectorized ---
  float m = -INFINITY, s = 0.0f;
  for (int i = threadIdx.x; i < Cn / 4; i += BDIM) {
    float4 v = x4[i];
    float vm = fmaxf(fmaxf(v.x, v.y), fmaxf(v.z, v.w));
    float mn = fmaxf(m, vm);
    s = s * __expf(m - mn)
      + __expf(v.x - mn) + __expf(v.y - mn)
      + __expf(v.z - mn) + __expf(v.w - mn);
    m = mn;
  }

  // --- wave (64-lane) butterfly reduce of (m, s) ---
  #pragma unroll
  for (int off = 1; off < 64; off <<= 1) {
    float m2 = __shfl_xor(m, off);
    float s2 = __shfl_xor(s, off);
    float mn = fmaxf(m, m2);
    s = s * __expf(m - mn) + s2 * __expf(m2 - mn);
    m = mn;
  }

  // --- cross-wave combine via LDS (4 waves) ---
  __shared__ float sm[BDIM / 64], ss[BDIM / 64];
  const int wave = threadIdx.x >> 6, lane = threadIdx.x & 63;
  if (lane == 0) { sm[wave] = m; ss[wave] = s; }
  __syncthreads();

  if (threadIdx.x == 0) {
    m = sm[0]; s = ss[0];
    #pragma unroll
    for (int w = 1; w < BDIM / 64; ++w) {
      float m2 = sm[w], s2 = ss[w];
      float mn = fmaxf(m, m2);
      s = s * __expf(m - mn) + s2 * __expf(m2 - mn);
      m = mn;
    }
    const float logZ = m + logf(s);

    const int* __restrict__ yr = y + (size_t)b * Tn;
    const int tgt = yr[0];
    const float x_tgt = xr[tgt];
    const float loss1 = logZ - x_tgt;

    // excluded set = {target} ∪ {valid rest}, deduped (T<=20, O(T^2) fine)
    int idxs[Tn];
    int n = 0;
    idxs[n++] = tgt;
    float x_rel = INFINITY;
    int nvalid = 0;
    for (int t = 1; t < Tn; ++t) {
      const int vi = yr[t];
      if (vi >= 0) {
        const float xv = xr[vi];
        x_rel = fminf(x_rel, xv);   // argmin-of-pred then gather == min value
        ++nvalid;
        bool dup = false;
        for (int k = 0; k < n; ++k) dup = dup || (idxs[k] == vi);
        if (!dup) idxs[n++] = vi;
      }
    }

    float loss2 = 0.0f, act = 0.0f;
    if (nvalid >= 1) {
      act = 1.0f;
      float exsum = 0.0f;
      for (int k = 0; k < n; ++k) exsum += __expf(xr[idxs[k]] - m);
      float s_cand = s - exsum;                  // remove excluded terms
      if (s_cand < 1e-30f) s_cand = 1e-30f;      // guard (can't trigger w/ C>>T)
      const float lse_cand = m + logf(s_cand);
      const float d = lse_cand - x_rel;
      // rel_loss = logaddexp(lse_cand, x_rel) - x_rel
      const float rel = (d >= 0.0f) ? (d + log1pf(__expf(-d)))
                                    : log1pf(__expf(d));
      loss2 = rel;
    }

    ws[b]          = loss1;
    ws[Bn + b]     = loss2;
    ws[2 * Bn + b] = act;
  }
}

// Kernel 2: reduce 1024 rows -> scalar loss
__global__ __launch_bounds__(256) void rll_final_kernel(
    const float* __restrict__ ws, float* __restrict__ out) {
  float s1 = 0.0f, s2 = 0.0f, sa = 0.0f;
  for (int i = threadIdx.x; i < Bn; i += 256) {
    s1 += ws[i];
    s2 += ws[Bn + i];
    sa += ws[2 * Bn + i];
  }
  #pragma unroll
  for (int off = 1; off < 64; off <<= 1) {
    s1 += __shfl_xor(s1, off);
    s2 += __shfl_xor(s2, off);
    sa += __shfl_xor(sa, off);
  }
  __shared__ float a1[4], a2[4], a3[4];
  const int wave = threadIdx.x >> 6, lane = threadIdx.x & 63;
  if (lane == 0) { a1[wave] = s1; a2[wave] = s2; a3[wave] = sa; }
  __syncthreads();
  if (threadIdx.x == 0) {
    s1 = a1[0] + a1[1] + a1[2] + a1[3];
    s2 = a2[0] + a2[1] + a2[2] + a2[3];
    sa = a3[0] + a3[1] + a3[2] + a3[3];
    out[0] = s1 / (float)Bn + GAMMA * (s2 / (1e-8f + sa));
  }
}

extern "C" void kernel_launch(void* const* d_in, const int* in_sizes, int n_in,
                              void* d_out, int out_size, void* d_ws, size_t ws_size,
                              hipStream_t stream) {
  const float* x = (const float*)d_in[0];
  const int*   y = (const int*)d_in[1];
  float* out = (float*)d_out;
  float* ws  = (float*)d_ws;

  rll_row_kernel<<<Bn, BDIM, 0, stream>>>(x, y, ws);
  rll_final_kernel<<<1, 256, 0, stream>>>(ws, out);
}

// Round 2
// 86.711 us; speedup vs baseline: 1.1253x; 1.1253x over previous
//
#include <hip/hip_runtime.h>
#include <math.h>

#define BDIM 256
constexpr float GAMMA = 0.2f;
constexpr int Bn = 1024;
constexpr int Cn = 100000;
constexpr int Tn = 20;
constexpr int N4 = Cn / 4;      // 25000 float4s per row
constexpr float THR = 30.0f;    // defer-max threshold: exp(30)*25000 ~ 2.5e17 << fp32 max

// Kernel 1: one block per row. Deferred-rescale online logsumexp, unroll x4.
__global__ __launch_bounds__(BDIM) void rll_row_kernel(
    const float* __restrict__ x, const int* __restrict__ y,
    float* __restrict__ ws) {
  const int b = blockIdx.x;
  const int tid = threadIdx.x;
  const float* __restrict__ xr = x + (size_t)b * Cn;
  const float4* __restrict__ x4 = reinterpret_cast<const float4*>(xr);

  // --- hoisted T-gather: 20 lanes load y + gathered x in parallel, stash in LDS ---
  __shared__ float s_xv[Tn];
  __shared__ int   s_yi[Tn];
  if (tid < Tn) {
    const int vi = y[(size_t)b * Tn + tid];
    s_yi[tid] = vi;
    const int safe = (vi >= 0) ? vi : 0;
    s_xv[tid] = xr[safe];                 // t=0 is target (always valid)
  }

  // --- deferred-rescale LSE: 4 independent accumulators, 4 loads in flight ---
  float m = -INFINITY;
  float s0 = 0.f, s1 = 0.f, s2 = 0.f, s3 = 0.f;

  int i = tid;
  for (; i + 3 * BDIM < N4; i += 4 * BDIM) {
    const float4 a = x4[i];
    const float4 bv = x4[i + BDIM];
    const float4 c = x4[i + 2 * BDIM];
    const float4 d = x4[i + 3 * BDIM];
    const float vm = fmaxf(
        fmaxf(fmaxf(fmaxf(a.x, a.y), fmaxf(a.z, a.w)),
              fmaxf(fmaxf(bv.x, bv.y), fmaxf(bv.z, bv.w))),
        fmaxf(fmaxf(fmaxf(c.x, c.y), fmaxf(c.z, c.w)),
              fmaxf(fmaxf(d.x, d.y), fmaxf(d.z, d.w))));
    if (vm > m + THR) {                   // rare: only when max grows by >THR
      const float sc = __expf(m - vm);    // first iter: exp(-inf)=0, s*=0 ok
      s0 *= sc; s1 *= sc; s2 *= sc; s3 *= sc;
      m = vm;
    }
    s0 += (__expf(a.x - m) + __expf(a.y - m)) + (__expf(a.z - m) + __expf(a.w - m));
    s1 += (__expf(bv.x - m) + __expf(bv.y - m)) + (__expf(bv.z - m) + __expf(bv.w - m));
    s2 += (__expf(c.x - m) + __expf(c.y - m)) + (__expf(c.z - m) + __expf(c.w - m));
    s3 += (__expf(d.x - m) + __expf(d.y - m)) + (__expf(d.z - m) + __expf(d.w - m));
  }
  for (; i < N4; i += BDIM) {
    const float4 a = x4[i];
    const float vm = fmaxf(fmaxf(a.x, a.y), fmaxf(a.z, a.w));
    if (vm > m + THR) {
      const float sc = __expf(m - vm);
      s0 *= sc; s1 *= sc; s2 *= sc; s3 *= sc;
      m = vm;
    }
    s0 += (__expf(a.x - m) + __expf(a.y - m)) + (__expf(a.z - m) + __expf(a.w - m));
  }
  float s = (s0 + s1) + (s2 + s3);

  // --- wave (64-lane) butterfly reduce of (m, s) ---
  #pragma unroll
  for (int off = 1; off < 64; off <<= 1) {
    const float m2 = __shfl_xor(m, off);
    const float q2 = __shfl_xor(s, off);
    const float mn = fmaxf(m, m2);
    s = s * __expf(m - mn) + q2 * __expf(m2 - mn);
    m = mn;
  }

  // --- cross-wave combine via LDS (4 waves) ---
  __shared__ float sm[BDIM / 64], ss[BDIM / 64];
  const int wave = tid >> 6, lane = tid & 63;
  if (lane == 0) { sm[wave] = m; ss[wave] = s; }
  __syncthreads();

  if (tid == 0) {
    m = sm[0]; s = ss[0];
    #pragma unroll
    for (int w = 1; w < BDIM / 64; ++w) {
      const float m2 = sm[w], q2 = ss[w];
      const float mn = fmaxf(m, m2);
      s = s * __expf(m - mn) + q2 * __expf(m2 - mn);
      m = mn;
    }
    const float logZ = m + logf(s);

    const int tgt = s_yi[0];
    const float loss1 = logZ - s_xv[0];

    // excluded set = {target} ∪ {valid rest}, deduped (T<=20, O(T^2), all LDS)
    int   idxs[Tn];
    float vals[Tn];
    int n = 0;
    idxs[n] = tgt; vals[n] = s_xv[0]; ++n;
    float x_rel = INFINITY;
    int nvalid = 0;
    for (int t = 1; t < Tn; ++t) {
      const int vi = s_yi[t];
      if (vi >= 0) {
        const float xv = s_xv[t];
        x_rel = fminf(x_rel, xv);       // argmin-of-pred then gather == min value
        ++nvalid;
        bool dup = false;
        for (int k = 0; k < n; ++k) dup = dup || (idxs[k] == vi);
        if (!dup) { idxs[n] = vi; vals[n] = xv; ++n; }
      }
    }

    float loss2 = 0.0f, act = 0.0f;
    if (nvalid >= 1) {
      act = 1.0f;
      float exsum = 0.0f;
      for (int k = 0; k < n; ++k) exsum += __expf(vals[k] - m);
      float s_cand = s - exsum;                   // remove excluded terms
      if (s_cand < 1e-30f) s_cand = 1e-30f;       // guard
      const float lse_cand = m + logf(s_cand);
      const float d = lse_cand - x_rel;
      // rel_loss = logaddexp(lse_cand, x_rel) - x_rel
      loss2 = (d >= 0.0f) ? (d + log1pf(__expf(-d))) : log1pf(__expf(d));
    }

    ws[b]          = loss1;
    ws[Bn + b]     = loss2;
    ws[2 * Bn + b] = act;
  }
}

// Kernel 2: reduce 1024 rows -> scalar loss
__global__ __launch_bounds__(256) void rll_final_kernel(
    const float* __restrict__ ws, float* __restrict__ out) {
  float s1 = 0.0f, s2 = 0.0f, sa = 0.0f;
  for (int i = threadIdx.x; i < Bn; i += 256) {
    s1 += ws[i];
    s2 += ws[Bn + i];
    sa += ws[2 * Bn + i];
  }
  #pragma unroll
  for (int off = 1; off < 64; off <<= 1) {
    s1 += __shfl_xor(s1, off);
    s2 += __shfl_xor(s2, off);
    sa += __shfl_xor(sa, off);
  }
  __shared__ float a1[4], a2[4], a3[4];
  const int wave = threadIdx.x >> 6, lane = threadIdx.x & 63;
  if (lane == 0) { a1[wave] = s1; a2[wave] = s2; a3[wave] = sa; }
  __syncthreads();
  if (threadIdx.x == 0) {
    s1 = a1[0] + a1[1] + a1[2] + a1[3];
    s2 = a2[0] + a2[1] + a2[2] + a2[3];
    sa = a3[0] + a3[1] + a3[2] + a3[3];
    out[0] = s1 / (float)Bn + GAMMA * (s2 / (1e-8f + sa));
  }
}

extern "C" void kernel_launch(void* const* d_in, const int* in_sizes, int n_in,
                              void* d_out, int out_size, void* d_ws, size_t ws_size,
                              hipStream_t stream) {
  const float* x = (const float*)d_in[0];
  const int*   y = (const int*)d_in[1];
  float* out = (float*)d_out;
  float* ws  = (float*)d_ws;

  rll_row_kernel<<<Bn, BDIM, 0, stream>>>(x, y, ws);
  rll_final_kernel<<<1, 256, 0, stream>>>(ws, out);
}